// Round 2
// baseline (575.854 us; speedup 1.0000x reference)
//
#include <hip/hip_runtime.h>

#define N_NODES 50000
#define N_EDGES 800000
#define HDIM 128
#define ODIM 64
#define NLAYER 3
#define NGRAPH 512
#define BN_EPS 1e-5f
#define BCAP 48          // bucket capacity; deg ~ Poisson(16), P(>=48) ~ 1e-9/node
#define NPAD 50048       // 782*64: padded row count for Y / gemm reads
#define SLA 800016       // slice stride (elems) for A: (N_NODES+1)*16  (+1 = zero sentinel row)
#define SLY 800768       // slice stride (elems) for Y: NPAD*16
#define NBLK 782         // mlp grid: ceil(50000/64)
#define GBLK 782
#define HPITCH 136
#define TPITCH 136
#define SCAN_BLK 196     // ceil(50000/256)
#define AGG_GRID 1568    // 8 slices * 196 node-blocks(256 nodes)

// k_prep block-range partition
#define SCAT_BLK 782     // 800000 edges / 4 per thread / 256
#define CVT_BLK 782      // 64-node tiles, LDS transpose to slice-major
#define CVTW_BLK 481     // 122880 weight elems + 128 sentinel zeros

typedef __attribute__((ext_vector_type(8))) short short8;
typedef __attribute__((ext_vector_type(8))) unsigned short ushort8;
typedef __attribute__((ext_vector_type(4))) float floatx4;

static __device__ __forceinline__ unsigned short f2bf(float f) {
    union { float f; unsigned int u; } v; v.f = f;
    unsigned int r = v.u + 0x7FFFu + ((v.u >> 16) & 1u);
    return (unsigned short)(r >> 16);
}
static __device__ __forceinline__ float bf2f(unsigned short s) {
    union { unsigned int u; float f; } v; v.u = ((unsigned int)s) << 16;
    return v.f;
}

// ---- fused prep: bucket scatter + f32->bf16 slice-major cvt + cvtW + sentinels ----

__global__ __launch_bounds__(256) void k_prep(
    const int* __restrict__ src, const int* __restrict__ dst,
    int* __restrict__ cnt, unsigned short* __restrict__ bucket,
    const float* __restrict__ x,
    const float* __restrict__ W1, const float* __restrict__ W2,
    const float* __restrict__ hW1, const float* __restrict__ hW2,
    unsigned short* __restrict__ wtb, unsigned short* __restrict__ A)
{
    __shared__ unsigned short sx[64 * HDIM];   // 16 KB transpose tile (cvt branch only)
    int b = blockIdx.x;
    int tid = threadIdx.x;
    if (b < SCAT_BLK) {
        int base = (b * 256 + tid) * 4;
        if (base < N_EDGES) {
            int4 s4 = *(const int4*)(src + base);
            int4 d4 = *(const int4*)(dst + base);
            int p0 = atomicAdd(&cnt[d4.x], 1);
            int p1 = atomicAdd(&cnt[d4.y], 1);
            int p2 = atomicAdd(&cnt[d4.z], 1);
            int p3 = atomicAdd(&cnt[d4.w], 1);
            if (p0 < BCAP) bucket[(size_t)d4.x * BCAP + p0] = (unsigned short)s4.x;
            if (p1 < BCAP) bucket[(size_t)d4.y * BCAP + p1] = (unsigned short)s4.y;
            if (p2 < BCAP) bucket[(size_t)d4.z * BCAP + p2] = (unsigned short)s4.z;
            if (p3 < BCAP) bucket[(size_t)d4.w * BCAP + p3] = (unsigned short)s4.w;
        }
    } else if (b < SCAT_BLK + CVT_BLK) {
        int nbase = (b - SCAT_BLK) * 64;
        // stage: 64 rows x 128 f32 -> bf16 LDS (coalesced float4 reads)
#pragma unroll
        for (int k = 0; k < 8; ++k) {
            int i = tid + k * 256;           // 2048 float4 tasks
            int row = i >> 5, c4 = i & 31;
            int gr = nbase + row;
            if (gr < N_NODES) {
                float4 v = *(const float4*)(x + (size_t)gr * HDIM + c4 * 4);
                ushort4 o = make_ushort4(f2bf(v.x), f2bf(v.y), f2bf(v.z), f2bf(v.w));
                *(ushort4*)&sx[row * HDIM + c4 * 4] = o;
            }
        }
        __syncthreads();
        // scatter to slice-major A: 16 (s,h) chunks x 64 nodes x 8 dims
#pragma unroll
        for (int k = 0; k < 4; ++k) {
            int u = tid + k * 256;           // 1024 tasks
            int sh = u >> 6, node = u & 63;
            int gr = nbase + node;
            if (gr < N_NODES) {
                int s = sh >> 1, h = sh & 1;
                *(short8*)(A + (size_t)s * SLA + (size_t)gr * 16 + h * 8) =
                    *(const short8*)&sx[node * HDIM + sh * 8];
            }
        }
    } else {
        int idx = (b - SCAT_BLK - CVT_BLK) * 256 + tid;
        if (idx < 6 * HDIM * HDIM) {
            // conv weights: mat 2l=W1[l], 2l+1=W2[l]; [k][n] -> [n][k] bf16
            int mat = idx >> 14;
            int rem = idx & 16383;
            int k = rem >> 7, n = rem & 127;
            int l = mat >> 1;
            const float* W = (mat & 1) ? (W2 + l * HDIM * HDIM) : (W1 + l * HDIM * HDIM);
            wtb[mat * HDIM * HDIM + n * HDIM + k] = f2bf(W[k * HDIM + n]);
        } else if (idx < 7 * HDIM * HDIM) {
            int j = idx - 6 * HDIM * HDIM;
            int n = j >> 7, k = j & 127;
            wtb[idx] = f2bf(hW1[k * HDIM + n]);
        } else if (idx < 7 * HDIM * HDIM + ODIM * HDIM) {
            int j = idx - 7 * HDIM * HDIM;
            int n = j >> 7, k = j & 127;   // n in [0,64)
            wtb[idx] = f2bf(hW2[k * ODIM + n]);
        } else if (idx < 7 * HDIM * HDIM + ODIM * HDIM + 128) {
            // zero sentinel row N_NODES in every A slice
            int j = idx - 7 * HDIM * HDIM - ODIM * HDIM;   // 0..127
            int s = j >> 4, e = j & 15;
            A[(size_t)s * SLA + (size_t)N_NODES * 16 + e] = 0;
        }
    }
}

// ---- CSR build: block sums -> serial scan -> local scan + compact copy ----

__global__ __launch_bounds__(256) void k_scan1(const int* __restrict__ cnt,
                                               int* __restrict__ bsum) {
    int b = blockIdx.x, tid = threadIdx.x;
    int n = b * 256 + tid;
    int v = (n < N_NODES) ? min(cnt[n], BCAP) : 0;
#pragma unroll
    for (int d = 32; d; d >>= 1) v += __shfl_down(v, d, 64);
    __shared__ int r[4];
    if ((tid & 63) == 0) r[tid >> 6] = v;
    __syncthreads();
    if (tid == 0) bsum[b] = r[0] + r[1] + r[2] + r[3];
}

__global__ void k_scan2(const int* __restrict__ bsum, int* __restrict__ bpre) {
    if (threadIdx.x == 0) {
        int acc = 0;
        for (int i = 0; i < SCAN_BLK; ++i) { bpre[i] = acc; acc += bsum[i]; }
        bpre[SCAN_BLK] = acc;
    }
}

__global__ __launch_bounds__(256) void k_compact(
    const int* __restrict__ cnt, const int* __restrict__ bpre,
    const unsigned short* __restrict__ bucket,
    int* __restrict__ off, unsigned short* __restrict__ cidx)
{
    int b = blockIdx.x, tid = threadIdx.x;
    int n = b * 256 + tid;
    int v = (n < N_NODES) ? min(cnt[n], BCAP) : 0;
    int lane = tid & 63, wv = tid >> 6;
    int s = v;
#pragma unroll
    for (int d = 1; d < 64; d <<= 1) {
        int t = __shfl_up(s, d, 64);
        if (lane >= d) s += t;
    }
    __shared__ int wsum[4];
    if (lane == 63) wsum[wv] = s;
    __syncthreads();
    int base = bpre[b];
#pragma unroll
    for (int w = 0; w < 4; ++w) if (w < wv) base += wsum[w];
    int o = base + s - v;    // exclusive position
    if (n < N_NODES) off[n] = o;
    if (n == N_NODES - 1) off[N_NODES] = o + v;
    for (int e = 0; e < v; ++e)
        cidx[o + e] = bucket[(size_t)n * BCAP + e];
}

// ---- XCD-sliced aggregate: block (slice s = b&7, 256 nodes); y = x + sum_nbr x ----
// Each XCD touches only its 1.6 MB x-slice (L2-resident) + the shared CSR stream.

__global__ __launch_bounds__(256) void k_agg(
    const unsigned short* __restrict__ A,
    const int* __restrict__ off,
    const unsigned short* __restrict__ cidx,
    unsigned short* __restrict__ Y)
{
    int b = blockIdx.x;
    int s = b & 7, nb = b >> 3;
    int node = nb * 256 + threadIdx.x;
    if (node >= NPAD) return;
    const unsigned short* xs = A + (size_t)s * SLA;
    unsigned short* ys = Y + (size_t)s * SLY;
    if (node >= N_NODES) {               // zero pad rows [N, NPAD)
        short8 z = (short8)0;
        *(short8*)(ys + (size_t)node * 16) = z;
        *(short8*)(ys + (size_t)node * 16 + 8) = z;
        return;
    }
    float acc[16];
    {
        short8 v0 = *(const short8*)(xs + (size_t)node * 16);
        short8 v1 = *(const short8*)(xs + (size_t)node * 16 + 8);
#pragma unroll
        for (int j = 0; j < 8; ++j) { acc[j] = bf2f((unsigned short)v0[j]); acc[8 + j] = bf2f((unsigned short)v1[j]); }
    }
    int o0 = off[node];
    int deg = off[node + 1] - o0;
    for (int e = 0; e < deg; e += 4) {
        int rem = deg - e;
        int ix[4];
#pragma unroll
        for (int j = 0; j < 4; ++j)
            ix[j] = (j < rem) ? (int)cidx[o0 + e + j] : N_NODES;
        short8 g0[4], g1[4];
#pragma unroll
        for (int j = 0; j < 4; ++j) {
            g0[j] = *(const short8*)(xs + (size_t)ix[j] * 16);
            g1[j] = *(const short8*)(xs + (size_t)ix[j] * 16 + 8);
        }
#pragma unroll
        for (int j = 0; j < 4; ++j) {
#pragma unroll
            for (int k = 0; k < 8; ++k) {
                acc[k]     += bf2f((unsigned short)g0[j][k]);
                acc[8 + k] += bf2f((unsigned short)g1[j][k]);
            }
        }
    }
    short8 w0, w1;
#pragma unroll
    for (int j = 0; j < 8; ++j) { w0[j] = (short)f2bf(acc[j]); w1[j] = (short)f2bf(acc[8 + j]); }
    *(short8*)(ys + (size_t)node * 16) = w0;
    *(short8*)(ys + (size_t)node * 16 + 8) = w1;
}

// ---- gemm1: h = y @ W1 + b1 (+fused BN stats); 64 nodes/block, 512 threads ----

__global__ __launch_bounds__(512, 6) void k_gml(
    const unsigned short* __restrict__ Y,
    const unsigned short* __restrict__ wt,   // [n][k] bf16
    const float* __restrict__ b1,
    unsigned short* __restrict__ hout,
    float* __restrict__ gstats)              // [256]: 128 sum + 128 sumsq
{
    __shared__ float s_sum[HDIM], s_sq[HDIM];
    __shared__ __align__(16) unsigned short yb[64 * TPITCH];
    int tid = threadIdx.x;
    if (tid < HDIM) { s_sum[tid] = 0.f; s_sq[tid] = 0.f; }
    int nbase = blockIdx.x * 64;

    // stage y tile from slice-major (rows < NPAD always valid)
#pragma unroll
    for (int t = tid; t < 1024; t += 512) {
        int nl = t & 63, tsub = t >> 6;
        int s = tsub >> 1, h = tsub & 1;
        *(short8*)&yb[nl * TPITCH + tsub * 8] =
            *(const short8*)(Y + (size_t)s * SLY + (size_t)(nbase + nl) * 16 + h * 8);
    }
    __syncthreads();

    int wv = tid >> 6, lane = tid & 63;
    int m = lane & 15, quad = lane >> 4;
    int mrow = (wv & 3) * 16 + m;
    int ncol0 = (wv >> 2) * 64;

    short8 a[4];
#pragma unroll
    for (int kk = 0; kk < 4; ++kk)
        a[kk] = *(const short8*)&yb[mrow * TPITCH + kk * 32 + quad * 8];
    __syncthreads();   // all A-frag reads complete before C overwrites yb

    floatx4 acc4[4];
#pragma unroll
    for (int nt = 0; nt < 4; ++nt) {
        floatx4 c = {0.f, 0.f, 0.f, 0.f};
#pragma unroll
        for (int kk = 0; kk < 4; ++kk) {
            short8 b = *(const short8*)(wt + (ncol0 + nt * 16 + m) * HDIM + kk * 32 + quad * 8);
            c = __builtin_amdgcn_mfma_f32_16x16x32_bf16(a[kk], b, c, 0, 0, 0);
        }
        acc4[nt] = c;
    }

    // epilogue: +b1, stats, C -> LDS
    int lrow0 = (wv & 3) * 16 + quad * 4;
#pragma unroll
    for (int nt = 0; nt < 4; ++nt) {
        int n = ncol0 + nt * 16 + m;
        float bias = b1[n];
        float ssum = 0.f, ssq = 0.f;
#pragma unroll
        for (int r = 0; r < 4; ++r) {
            float val = acc4[nt][r] + bias;
            yb[(lrow0 + r) * TPITCH + n] = f2bf(val);
            if (nbase + lrow0 + r < N_NODES) { ssum += val; ssq += val * val; }
        }
        atomicAdd(&s_sum[n], ssum);
        atomicAdd(&s_sq[n], ssq);
    }
    __syncthreads();
    if (tid < HDIM) {
        atomicAdd(&gstats[tid], s_sum[tid]);
        atomicAdd(&gstats[HDIM + tid], s_sq[tid]);
    }
    // coalesced plain store: 8 threads/row, 32 B each
    int lrow = tid >> 3, off2 = (tid & 7) * 16;
    int grow = nbase + lrow;
    if (grow < N_NODES) {
        *(short8*)(hout + (size_t)grow * HDIM + off2) = *(const short8*)&yb[lrow * TPITCH + off2];
        *(short8*)(hout + (size_t)grow * HDIM + off2 + 8) = *(const short8*)&yb[lrow * TPITCH + off2 + 8];
    }
}

// ------- mlp2: x' = relu(BN(h)) @ W2 + b2, relu; slice-major C store -------

__global__ __launch_bounds__(256) void k_mlp2(
    const unsigned short* __restrict__ hin,
    const float* __restrict__ stats,
    const float* __restrict__ gamma,
    const float* __restrict__ beta,
    const unsigned short* __restrict__ wt,   // [n][k] bf16
    const float* __restrict__ b2,
    unsigned short* __restrict__ A)          // slice-major out
{
    __shared__ float s_scale[HDIM], s_shift[HDIM];
    __shared__ __align__(16) unsigned short tb[64 * TPITCH];
    int tid = threadIdx.x;
    if (tid < HDIM) {
        float mu = stats[tid] * (1.f / N_NODES);
        float var = stats[HDIM + tid] * (1.f / N_NODES) - mu * mu;
        float sc = gamma[tid] * rsqrtf(var + BN_EPS);
        s_scale[tid] = sc;
        s_shift[tid] = beta[tid] - mu * sc;
    }
    __syncthreads();

    int wv = tid >> 6, lane = tid & 63;
    int m = lane & 15, quad = lane >> 4;
    int row0 = blockIdx.x * 64 + wv * 16;
    int arow = row0 + m;

    short8 a[4];
    if (arow < N_NODES) {
#pragma unroll
        for (int kk = 0; kk < 4; ++kk) {
            short8 v = *(const short8*)(hin + (size_t)arow * HDIM + kk * 32 + quad * 8);
            int c0 = kk * 32 + quad * 8;
            short8 af;
#pragma unroll
            for (int j = 0; j < 8; ++j) {
                float f = fmaxf(bf2f((unsigned short)v[j]) * s_scale[c0 + j] + s_shift[c0 + j], 0.f);
                af[j] = (short)f2bf(f);
            }
            a[kk] = af;
        }
    } else {
#pragma unroll
        for (int kk = 0; kk < 4; ++kk) a[kk] = (short8)0;
    }

    floatx4 acc[8];
#pragma unroll
    for (int nt = 0; nt < 8; ++nt) {
        floatx4 c = {0.f, 0.f, 0.f, 0.f};
#pragma unroll
        for (int kk = 0; kk < 4; ++kk) {
            short8 b = *(const short8*)(wt + (nt * 16 + m) * HDIM + kk * 32 + quad * 8);
            c = __builtin_amdgcn_mfma_f32_16x16x32_bf16(a[kk], b, c, 0, 0, 0);
        }
        acc[nt] = c;
    }

    int lrow0 = wv * 16 + quad * 4;
#pragma unroll
    for (int nt = 0; nt < 8; ++nt) {
        int n = nt * 16 + m;
        float bias = b2[n];
#pragma unroll
        for (int r = 0; r < 4; ++r)
            tb[(lrow0 + r) * TPITCH + n] = f2bf(fmaxf(acc[nt][r] + bias, 0.f));
    }
    __syncthreads();
    int lrow = tid >> 2, offd = (tid & 3) * 32;
    int grow = blockIdx.x * 64 + lrow;
    if (grow < N_NODES) {
#pragma unroll
        for (int i = 0; i < 4; ++i) {
            int d0 = offd + i * 8;
            int s = d0 >> 4, h = (d0 >> 3) & 1;
            *(short8*)(A + (size_t)s * SLA + (size_t)grow * 16 + h * 8) =
                *(const short8*)&tb[lrow * TPITCH + d0];
        }
    }
}

// ---------------- pool: g[gid] = sum of node rows (slice-major in) ----------

__global__ __launch_bounds__(256) void k_pool(
    const unsigned short* __restrict__ A,
    const int* __restrict__ batch,
    unsigned short* __restrict__ g)
{
    __shared__ float red[16][HDIM];
    int gid = blockIdx.x;
    int tid = threadIdx.x;

    int lo = 0, hi = N_NODES;
    while (lo < hi) { int mid = (lo + hi) >> 1; if (batch[mid] < gid) lo = mid + 1; else hi = mid; }
    int start = lo;
    int lo2 = start, hi2 = N_NODES;
    while (lo2 < hi2) { int mid = (lo2 + hi2) >> 1; if (batch[mid] < gid + 1) lo2 = mid + 1; else hi2 = mid; }
    int end = lo2;

    int tsub = tid & 15, rgrp = tid >> 4;
    int seg = tsub * 8;
    int s = tsub >> 1, h = tsub & 1;
    const unsigned short* xs = A + (size_t)s * SLA + h * 8;
    float acc[8] = {0.f, 0.f, 0.f, 0.f, 0.f, 0.f, 0.f, 0.f};
    for (int r = start + rgrp; r < end; r += 16) {
        short8 v = *(const short8*)(xs + (size_t)r * 16);
#pragma unroll
        for (int j = 0; j < 8; ++j) acc[j] += bf2f((unsigned short)v[j]);
    }
#pragma unroll
    for (int j = 0; j < 8; ++j) red[rgrp][seg + j] = acc[j];
    __syncthreads();
    if (tid < HDIM) {
        float sacc = 0.f;
#pragma unroll
        for (int i = 0; i < 16; ++i) sacc += red[i][tid];
        g[gid * HDIM + tid] = f2bf(sacc);
    }
}

// ---------------- head: out = relu(g@hW1+b1) @ hW2 + b2 (block-local) -------

__global__ __launch_bounds__(256) void k_head(
    const unsigned short* __restrict__ g,
    const unsigned short* __restrict__ w1t,  // [128][128] bf16 [n][k]
    const float* __restrict__ b1,
    const unsigned short* __restrict__ w2t,  // [64][128] bf16 [n][k]
    const float* __restrict__ b2,
    float* __restrict__ out)
{
    __shared__ unsigned short tb[64 * HPITCH];
    int tid = threadIdx.x;
    int wv = tid >> 6, lane = tid & 63;
    int m = lane & 15, quad = lane >> 4;
    int row0 = blockIdx.x * 64 + wv * 16;

    short8 a[4];
#pragma unroll
    for (int kk = 0; kk < 4; ++kk)
        a[kk] = *(const short8*)(g + (size_t)(row0 + m) * HDIM + kk * 32 + quad * 8);

    // stage 1: t = relu(g @ W1 + b1), 64x128, staged to LDS
#pragma unroll
    for (int nt = 0; nt < 8; ++nt) {
        floatx4 c = {0.f, 0.f, 0.f, 0.f};
#pragma unroll
        for (int kk = 0; kk < 4; ++kk) {
            short8 b = *(const short8*)(w1t + (nt * 16 + m) * HDIM + kk * 32 + quad * 8);
            c = __builtin_amdgcn_mfma_f32_16x16x32_bf16(a[kk], b, c, 0, 0, 0);
        }
        int n = nt * 16 + m;
        float bias = b1[n];
#pragma unroll
        for (int r = 0; r < 4; ++r) {
            int lrow = wv * 16 + quad * 4 + r;
            tb[lrow * HPITCH + n] = f2bf(fmaxf(c[r] + bias, 0.f));
        }
    }
    __syncthreads();

    // stage 2: out = t @ W2 + b2, 64x64
    short8 a2[4];
#pragma unroll
    for (int kk = 0; kk < 4; ++kk)
        a2[kk] = *(const short8*)&tb[(wv * 16 + m) * HPITCH + kk * 32 + quad * 8];

#pragma unroll
    for (int nt = 0; nt < 4; ++nt) {
        floatx4 c = {0.f, 0.f, 0.f, 0.f};
#pragma unroll
        for (int kk = 0; kk < 4; ++kk) {
            short8 b = *(const short8*)(w2t + (nt * 16 + m) * HDIM + kk * 32 + quad * 8);
            c = __builtin_amdgcn_mfma_f32_16x16x32_bf16(a2[kk], b, c, 0, 0, 0);
        }
        int n = nt * 16 + m;
        float bias = b2[n];
#pragma unroll
        for (int r = 0; r < 4; ++r) {
            int row = row0 + quad * 4 + r;
            out[(size_t)row * ODIM + n] = c[r] + bias;
        }
    }
}

// ---------------- launch ----------------

extern "C" void kernel_launch(void* const* d_in, const int* in_sizes, int n_in,
                              void* d_out, int out_size, void* d_ws, size_t ws_size,
                              hipStream_t stream) {
    const float* x        = (const float*)d_in[0];
    const float* conv_W1  = (const float*)d_in[1];
    const float* conv_b1  = (const float*)d_in[2];
    const float* conv_g   = (const float*)d_in[3];
    const float* conv_be  = (const float*)d_in[4];
    const float* conv_W2  = (const float*)d_in[5];
    const float* conv_b2  = (const float*)d_in[6];
    const float* head_W1  = (const float*)d_in[7];
    const float* head_b1  = (const float*)d_in[8];
    const float* head_W2  = (const float*)d_in[9];
    const float* head_b2  = (const float*)d_in[10];
    const int*   edges    = (const int*)d_in[11];   // [0..E)=src, [E..2E)=dst
    const int*   batch    = (const int*)d_in[12];

    char* ws = (char*)d_ws;
    int*            cnt    = (int*)(ws + 0);                    // 200,000 B
    float*          stats  = (float*)(ws + 200000);             // 3*256*4 = 3,072 B
    int*            bsum   = (int*)(ws + 203072);               // 196*4
    int*            bpre   = (int*)(ws + 203856);               // 197*4
    int*            off    = (int*)(ws + 204672);               // 50001*4 = 200,004 B
    unsigned short* cidx   = (unsigned short*)(ws + 404688);    // 800,008*2 = 1,600,016 B
    unsigned short* wtb    = (unsigned short*)(ws + 2004704);   // 245,760 B
    unsigned short* gbuf   = (unsigned short*)(ws + 2250464);   // 131,072 B
    unsigned short* A      = (unsigned short*)(ws + 2381536);   // 8*SLA*2 = 12,800,256 B
    unsigned short* Y      = (unsigned short*)(ws + 15181792);  // 8*SLY*2 = 12,812,288 B
    unsigned short* bucket = Y;                                 // overlay: 4,800,000 B, prep-only
    unsigned short* B      = (unsigned short*)(ws + 27994080);  // NPAD*128*2 = 12,812,288 B
    (void)in_sizes; (void)n_in; (void)out_size; (void)ws_size;  // total ~40.8 MB

    hipMemsetAsync(ws, 0, 203072, stream);                      // cnt + stats (atomic targets)

    k_prep<<<SCAT_BLK + CVT_BLK + CVTW_BLK, 256, 0, stream>>>(
        edges, edges + N_EDGES, cnt, bucket, x,
        conv_W1, conv_W2, head_W1, head_W2, wtb, A);
    k_scan1<<<SCAN_BLK, 256, 0, stream>>>(cnt, bsum);
    k_scan2<<<1, 64, 0, stream>>>(bsum, bpre);
    k_compact<<<SCAN_BLK, 256, 0, stream>>>(cnt, bpre, bucket, off, cidx);

    for (int l = 0; l < NLAYER; ++l) {
        k_agg<<<AGG_GRID, 256, 0, stream>>>(A, off, cidx, Y);
        k_gml<<<GBLK, 512, 0, stream>>>(Y, wtb + (2 * l) * HDIM * HDIM,
                                        conv_b1 + l * HDIM, B, stats + l * 256);
        k_mlp2<<<NBLK, 256, 0, stream>>>(B, stats + l * 256,
                                         conv_g + l * HDIM, conv_be + l * HDIM,
                                         wtb + (2 * l + 1) * HDIM * HDIM,
                                         conv_b2 + l * HDIM, A);
    }

    k_pool<<<NGRAPH, 256, 0, stream>>>(A, batch, gbuf);
    k_head<<<NGRAPH / 64, 256, 0, stream>>>(gbuf, wtb + 6 * HDIM * HDIM, head_b1,
                                            wtb + 7 * HDIM * HDIM, head_b2,
                                            (float*)d_out);
}

// Round 3
// 452.541 us; speedup vs baseline: 1.2725x; 1.2725x over previous
//
#include <hip/hip_runtime.h>

#define N_NODES 50000
#define N_EDGES 800000
#define HDIM 128
#define ODIM 64
#define NLAYER 3
#define NGRAPH 512
#define BN_EPS 1e-5f
#define BCAP 48      // bucket capacity; deg ~ Poisson(16), P(deg>=48) ~ 1e-9/node
#define NBLK 782     // mlp grid: ceil(50000/64)
#define GBLK 782     // gml grid: ceil(50000/64)
#define HPITCH 136   // LDS pitch for head t-tile
#define TPITCH 136   // LDS pitch for y/C tiles

// k_prep block-range partition
#define SCAT_BLK 782            // 800000 edges / 4 per thread / 256
#define CVT_BLK 6250            // 1.6M float4
#define CVTW_BLK 481            // 122880 weight elems + 256 sentinel zeros

typedef __attribute__((ext_vector_type(8))) short short8;
typedef __attribute__((ext_vector_type(8))) unsigned short ushort8;
typedef __attribute__((ext_vector_type(4))) float floatx4;

static __device__ __forceinline__ unsigned short f2bf(float f) {
    union { float f; unsigned int u; } v; v.f = f;
    unsigned int r = v.u + 0x7FFFu + ((v.u >> 16) & 1u);
    return (unsigned short)(r >> 16);
}
static __device__ __forceinline__ float bf2f(unsigned short s) {
    union { unsigned int u; float f; } v; v.u = ((unsigned int)s) << 16;
    return v.f;
}

// ---- fused prep: scatter (4 edges/thread) + cvt + cvtW + sentinel zero ----

__global__ __launch_bounds__(256) void k_prep(
    const int* __restrict__ src, const int* __restrict__ dst,
    int* __restrict__ cnt, unsigned short* __restrict__ colidx,
    const float* __restrict__ x, unsigned short* __restrict__ xb,
    const float* __restrict__ W1, const float* __restrict__ W2,
    const float* __restrict__ hW1, const float* __restrict__ hW2,
    unsigned short* __restrict__ wtb, unsigned short* __restrict__ xa2)
{
    int b = blockIdx.x;
    int tid = threadIdx.x;
    if (b < SCAT_BLK) {
        int base = (b * 256 + tid) * 4;
        if (base < N_EDGES) {
            int4 s4 = *(const int4*)(src + base);
            int4 d4 = *(const int4*)(dst + base);
            int p0 = atomicAdd(&cnt[d4.x], 1);
            int p1 = atomicAdd(&cnt[d4.y], 1);
            int p2 = atomicAdd(&cnt[d4.z], 1);
            int p3 = atomicAdd(&cnt[d4.w], 1);
            if (p0 < BCAP) colidx[d4.x * BCAP + p0] = (unsigned short)s4.x;
            if (p1 < BCAP) colidx[d4.y * BCAP + p1] = (unsigned short)s4.y;
            if (p2 < BCAP) colidx[d4.z * BCAP + p2] = (unsigned short)s4.z;
            if (p3 < BCAP) colidx[d4.w * BCAP + p3] = (unsigned short)s4.w;
        }
    } else if (b < SCAT_BLK + CVT_BLK) {
        int i = (b - SCAT_BLK) * 256 + tid;
        if (i < N_NODES * HDIM / 4) {
            float4 v = ((const float4*)x)[i];
            ushort4 o = make_ushort4(f2bf(v.x), f2bf(v.y), f2bf(v.z), f2bf(v.w));
            ((ushort4*)xb)[i] = o;
        }
    } else {
        int idx = (b - SCAT_BLK - CVT_BLK) * 256 + tid;
        if (idx < 6 * HDIM * HDIM) {
            // conv weights: mat 2l=W1[l], 2l+1=W2[l]; [k][n] -> [n][k] bf16
            int mat = idx >> 14;
            int rem = idx & 16383;
            int k = rem >> 7, n = rem & 127;
            int l = mat >> 1;
            const float* W = (mat & 1) ? (W2 + l * HDIM * HDIM) : (W1 + l * HDIM * HDIM);
            wtb[mat * HDIM * HDIM + n * HDIM + k] = f2bf(W[k * HDIM + n]);
        } else if (idx < 7 * HDIM * HDIM) {
            int j = idx - 6 * HDIM * HDIM;
            int n = j >> 7, k = j & 127;
            wtb[idx] = f2bf(hW1[k * HDIM + n]);
        } else if (idx < 7 * HDIM * HDIM + ODIM * HDIM) {
            int j = idx - 7 * HDIM * HDIM;
            int n = j >> 7, k = j & 127;   // n in [0,64)
            wtb[idx] = f2bf(hW2[k * ODIM + n]);
        } else if (idx < 7 * HDIM * HDIM + ODIM * HDIM + HDIM) {
            xb[(size_t)N_NODES * HDIM + (idx - 7 * HDIM * HDIM - ODIM * HDIM)] = 0;
        } else if (idx < 7 * HDIM * HDIM + ODIM * HDIM + 2 * HDIM) {
            xa2[(size_t)N_NODES * HDIM + (idx - 7 * HDIM * HDIM - ODIM * HDIM - HDIM)] = 0;
        }
    }
}

// pad each bucket to a multiple of 8 with sentinel row N_NODES (zero row)
__global__ __launch_bounds__(256) void k_pad(const int* __restrict__ cnt,
                                             unsigned short* __restrict__ colidx) {
    int n = blockIdx.x * 256 + threadIdx.x;
    if (n < N_NODES) {
        int d = cnt[n]; if (d > BCAP) d = BCAP;
        int end = (d + 7) & ~7;
        for (int i = d; i < end; ++i) colidx[n * BCAP + i] = (unsigned short)N_NODES;
    }
}

// ---- fused gather + mlp1: 64 nodes/block, 512 threads ----
// Phase1: 1024 gather tasks (node,16B-seg), 2 sequential per thread, unroll-8.
// Phase2: 8 waves, wave w -> rows (w&3)*16.., cols (w>>2)*64..; LDS tile reused.
// BN stats fold into epilogue: LDS reduce then one global atomic per column.

__global__ __launch_bounds__(512, 6) void k_gml(
    const unsigned short* __restrict__ x,
    const int* __restrict__ cnt,
    const unsigned short* __restrict__ colidx,
    const unsigned short* __restrict__ wt,   // [n][k] bf16
    const float* __restrict__ b1,
    unsigned short* __restrict__ hout,
    float* __restrict__ gstats)              // [256]: 128 sum + 128 sumsq
{
    __shared__ float s_sum[HDIM], s_sq[HDIM];
    __shared__ __align__(16) unsigned short yb[64 * TPITCH];
    int tid = threadIdx.x;
    if (tid < HDIM) { s_sum[tid] = 0.f; s_sq[tid] = 0.f; }
    int nbase = blockIdx.x * 64;

    // ---- gather into LDS ----
#pragma unroll
    for (int t = tid; t < 1024; t += 512) {
        int nl = t >> 4;
        int seg = (t & 15) * 8;
        int gnode = nbase + nl;
        float acc[8] = {0.f, 0.f, 0.f, 0.f, 0.f, 0.f, 0.f, 0.f};
        if (gnode < N_NODES) {
            short8 v = *(const short8*)(x + (size_t)gnode * HDIM + seg);
#pragma unroll
            for (int j = 0; j < 8; ++j) acc[j] = bf2f((unsigned short)v[j]);
            int deg = cnt[gnode]; if (deg > BCAP) deg = BCAP;
            int e = gnode * BCAP;
            int end = e + ((deg + 7) & ~7);
            for (; e < end; e += 8) {
                ushort8 i0 = *(const ushort8*)(colidx + e);
                short8 v0 = *(const short8*)(x + (size_t)i0[0] * HDIM + seg);
                short8 v1 = *(const short8*)(x + (size_t)i0[1] * HDIM + seg);
                short8 v2 = *(const short8*)(x + (size_t)i0[2] * HDIM + seg);
                short8 v3 = *(const short8*)(x + (size_t)i0[3] * HDIM + seg);
                short8 v4 = *(const short8*)(x + (size_t)i0[4] * HDIM + seg);
                short8 v5 = *(const short8*)(x + (size_t)i0[5] * HDIM + seg);
                short8 v6 = *(const short8*)(x + (size_t)i0[6] * HDIM + seg);
                short8 v7 = *(const short8*)(x + (size_t)i0[7] * HDIM + seg);
#pragma unroll
                for (int j = 0; j < 8; ++j)
                    acc[j] += ((bf2f((unsigned short)v0[j]) + bf2f((unsigned short)v1[j])) +
                               (bf2f((unsigned short)v2[j]) + bf2f((unsigned short)v3[j]))) +
                              ((bf2f((unsigned short)v4[j]) + bf2f((unsigned short)v5[j])) +
                               (bf2f((unsigned short)v6[j]) + bf2f((unsigned short)v7[j])));
            }
        }
        short8 o;
#pragma unroll
        for (int j = 0; j < 8; ++j) o[j] = (short)f2bf(acc[j]);
        *(short8*)&yb[nl * TPITCH + seg] = o;
    }
    __syncthreads();

    // ---- MFMA: h = y @ W1 ----
    int wv = tid >> 6, lane = tid & 63;
    int m = lane & 15, quad = lane >> 4;
    int mrow = (wv & 3) * 16 + m;
    int ncol0 = (wv >> 2) * 64;

    short8 a[4];
#pragma unroll
    for (int kk = 0; kk < 4; ++kk)
        a[kk] = *(const short8*)&yb[mrow * TPITCH + kk * 32 + quad * 8];
    __syncthreads();   // all A-frag reads complete before C overwrites yb

    floatx4 acc4[4];
#pragma unroll
    for (int nt = 0; nt < 4; ++nt) {
        floatx4 c = {0.f, 0.f, 0.f, 0.f};
#pragma unroll
        for (int kk = 0; kk < 4; ++kk) {
            short8 b = *(const short8*)(wt + (ncol0 + nt * 16 + m) * HDIM + kk * 32 + quad * 8);
            c = __builtin_amdgcn_mfma_f32_16x16x32_bf16(a[kk], b, c, 0, 0, 0);
        }
        acc4[nt] = c;
    }

    // epilogue: +b1, stats, C -> LDS
    int lrow0 = (wv & 3) * 16 + quad * 4;
#pragma unroll
    for (int nt = 0; nt < 4; ++nt) {
        int n = ncol0 + nt * 16 + m;
        float bias = b1[n];
        float ssum = 0.f, ssq = 0.f;
#pragma unroll
        for (int r = 0; r < 4; ++r) {
            float val = acc4[nt][r] + bias;
            yb[(lrow0 + r) * TPITCH + n] = f2bf(val);
            if (nbase + lrow0 + r < N_NODES) { ssum += val; ssq += val * val; }
        }
        atomicAdd(&s_sum[n], ssum);
        atomicAdd(&s_sq[n], ssq);
    }
    __syncthreads();
    if (tid < HDIM) {
        // one device-scope atomic per column per block (replaces k_stats pass)
        atomicAdd(&gstats[tid], s_sum[tid]);
        atomicAdd(&gstats[HDIM + tid], s_sq[tid]);
    }
    // coalesced store: 8 threads/row, 32 B each
    int lrow = tid >> 3, off = (tid & 7) * 16;
    int grow = nbase + lrow;
    if (grow < N_NODES) {
        *(short8*)(hout + (size_t)grow * HDIM + off) = *(const short8*)&yb[lrow * TPITCH + off];
        *(short8*)(hout + (size_t)grow * HDIM + off + 8) = *(const short8*)&yb[lrow * TPITCH + off + 8];
    }
}

// ------- mlp2: x' = relu(BN(h) relu'd @ W2 + b2); LDS-staged C store -------

__global__ __launch_bounds__(256) void k_mlp2(
    const unsigned short* __restrict__ hin,
    const float* __restrict__ stats,
    const float* __restrict__ gamma,
    const float* __restrict__ beta,
    const unsigned short* __restrict__ wt,   // [n][k] bf16
    const float* __restrict__ b2,
    unsigned short* __restrict__ xout)
{
    __shared__ float s_scale[HDIM], s_shift[HDIM];
    __shared__ __align__(16) unsigned short tb[64 * TPITCH];
    int tid = threadIdx.x;
    if (tid < HDIM) {
        float mu = stats[tid] * (1.f / N_NODES);
        float var = stats[HDIM + tid] * (1.f / N_NODES) - mu * mu;
        float sc = gamma[tid] * rsqrtf(var + BN_EPS);
        s_scale[tid] = sc;
        s_shift[tid] = beta[tid] - mu * sc;
    }
    __syncthreads();

    int wv = tid >> 6, lane = tid & 63;
    int m = lane & 15, quad = lane >> 4;
    int row0 = blockIdx.x * 64 + wv * 16;
    int arow = row0 + m;

    short8 a[4];
    if (arow < N_NODES) {
#pragma unroll
        for (int kk = 0; kk < 4; ++kk) {
            short8 v = *(const short8*)(hin + (size_t)arow * HDIM + kk * 32 + quad * 8);
            int c0 = kk * 32 + quad * 8;
            short8 af;
#pragma unroll
            for (int j = 0; j < 8; ++j) {
                float f = fmaxf(bf2f((unsigned short)v[j]) * s_scale[c0 + j] + s_shift[c0 + j], 0.f);
                af[j] = (short)f2bf(f);
            }
            a[kk] = af;
        }
    } else {
#pragma unroll
        for (int kk = 0; kk < 4; ++kk) a[kk] = (short8)0;
    }

    floatx4 acc[8];
#pragma unroll
    for (int nt = 0; nt < 8; ++nt) {
        floatx4 c = {0.f, 0.f, 0.f, 0.f};
#pragma unroll
        for (int kk = 0; kk < 4; ++kk) {
            short8 b = *(const short8*)(wt + (nt * 16 + m) * HDIM + kk * 32 + quad * 8);
            c = __builtin_amdgcn_mfma_f32_16x16x32_bf16(a[kk], b, c, 0, 0, 0);
        }
        acc[nt] = c;
    }

    int lrow0 = wv * 16 + quad * 4;
#pragma unroll
    for (int nt = 0; nt < 8; ++nt) {
        int n = nt * 16 + m;
        float bias = b2[n];
#pragma unroll
        for (int r = 0; r < 4; ++r)
            tb[(lrow0 + r) * TPITCH + n] = f2bf(fmaxf(acc[nt][r] + bias, 0.f));
    }
    __syncthreads();
    int lrow = tid >> 2, off = (tid & 3) * 32;
    int grow = blockIdx.x * 64 + lrow;
    if (grow < N_NODES) {
#pragma unroll
        for (int i = 0; i < 4; ++i)
            *(short8*)(xout + (size_t)grow * HDIM + off + i * 8) =
                *(const short8*)&tb[lrow * TPITCH + off + i * 8];
    }
}

// ---------------- pool: g[gid] = sum of node rows (bf16 out) ----------------

__global__ __launch_bounds__(256) void k_pool(
    const unsigned short* __restrict__ xf,
    const int* __restrict__ batch,
    unsigned short* __restrict__ g)
{
    __shared__ float red[16][HDIM];
    int gid = blockIdx.x;
    int tid = threadIdx.x;

    int lo = 0, hi = N_NODES;
    while (lo < hi) { int mid = (lo + hi) >> 1; if (batch[mid] < gid) lo = mid + 1; else hi = mid; }
    int start = lo;
    int lo2 = start, hi2 = N_NODES;
    while (lo2 < hi2) { int mid = (lo2 + hi2) >> 1; if (batch[mid] < gid + 1) lo2 = mid + 1; else hi2 = mid; }
    int end = lo2;

    int tsub = tid & 15, rgrp = tid >> 4;
    int seg = tsub * 8;
    float acc[8] = {0.f, 0.f, 0.f, 0.f, 0.f, 0.f, 0.f, 0.f};
    for (int r = start + rgrp; r < end; r += 16) {
        short8 v = *(const short8*)(xf + (size_t)r * HDIM + seg);
#pragma unroll
        for (int j = 0; j < 8; ++j) acc[j] += bf2f((unsigned short)v[j]);
    }
#pragma unroll
    for (int j = 0; j < 8; ++j) red[rgrp][seg + j] = acc[j];
    __syncthreads();
    if (tid < HDIM) {
        float s = 0.f;
#pragma unroll
        for (int i = 0; i < 16; ++i) s += red[i][tid];
        g[gid * HDIM + tid] = f2bf(s);
    }
}

// ---------------- head: out = relu(g@hW1+b1) @ hW2 + b2 (block-local) -------

__global__ __launch_bounds__(256) void k_head(
    const unsigned short* __restrict__ g,
    const unsigned short* __restrict__ w1t,  // [128][128] bf16 [n][k]
    const float* __restrict__ b1,
    const unsigned short* __restrict__ w2t,  // [64][128] bf16 [n][k]
    const float* __restrict__ b2,
    float* __restrict__ out)
{
    __shared__ unsigned short tb[64 * HPITCH];
    int tid = threadIdx.x;
    int wv = tid >> 6, lane = tid & 63;
    int m = lane & 15, quad = lane >> 4;
    int row0 = blockIdx.x * 64 + wv * 16;

    short8 a[4];
#pragma unroll
    for (int kk = 0; kk < 4; ++kk)
        a[kk] = *(const short8*)(g + (size_t)(row0 + m) * HDIM + kk * 32 + quad * 8);

    // stage 1: t = relu(g @ W1 + b1), 64x128, staged to LDS
#pragma unroll
    for (int nt = 0; nt < 8; ++nt) {
        floatx4 c = {0.f, 0.f, 0.f, 0.f};
#pragma unroll
        for (int kk = 0; kk < 4; ++kk) {
            short8 b = *(const short8*)(w1t + (nt * 16 + m) * HDIM + kk * 32 + quad * 8);
            c = __builtin_amdgcn_mfma_f32_16x16x32_bf16(a[kk], b, c, 0, 0, 0);
        }
        int n = nt * 16 + m;
        float bias = b1[n];
#pragma unroll
        for (int r = 0; r < 4; ++r) {
            int lrow = wv * 16 + quad * 4 + r;
            tb[lrow * HPITCH + n] = f2bf(fmaxf(c[r] + bias, 0.f));
        }
    }
    __syncthreads();

    // stage 2: out = t @ W2 + b2, 64x64
    short8 a2[4];
#pragma unroll
    for (int kk = 0; kk < 4; ++kk)
        a2[kk] = *(const short8*)&tb[(wv * 16 + m) * HPITCH + kk * 32 + quad * 8];

#pragma unroll
    for (int nt = 0; nt < 4; ++nt) {
        floatx4 c = {0.f, 0.f, 0.f, 0.f};
#pragma unroll
        for (int kk = 0; kk < 4; ++kk) {
            short8 b = *(const short8*)(w2t + (nt * 16 + m) * HDIM + kk * 32 + quad * 8);
            c = __builtin_amdgcn_mfma_f32_16x16x32_bf16(a2[kk], b, c, 0, 0, 0);
        }
        int n = nt * 16 + m;
        float bias = b2[n];
#pragma unroll
        for (int r = 0; r < 4; ++r) {
            int row = row0 + quad * 4 + r;
            out[(size_t)row * ODIM + n] = c[r] + bias;
        }
    }
}

// ---------------- launch ----------------

extern "C" void kernel_launch(void* const* d_in, const int* in_sizes, int n_in,
                              void* d_out, int out_size, void* d_ws, size_t ws_size,
                              hipStream_t stream) {
    const float* x        = (const float*)d_in[0];
    const float* conv_W1  = (const float*)d_in[1];
    const float* conv_b1  = (const float*)d_in[2];
    const float* conv_g   = (const float*)d_in[3];
    const float* conv_be  = (const float*)d_in[4];
    const float* conv_W2  = (const float*)d_in[5];
    const float* conv_b2  = (const float*)d_in[6];
    const float* head_W1  = (const float*)d_in[7];
    const float* head_b1  = (const float*)d_in[8];
    const float* head_W2  = (const float*)d_in[9];
    const float* head_b2  = (const float*)d_in[10];
    const int*   edges    = (const int*)d_in[11];   // [0..E)=src, [E..2E)=dst
    const int*   batch    = (const int*)d_in[12];

    char* ws = (char*)d_ws;
    int*            cnt    = (int*)(ws + 0);                    // 200,000 B
    float*          stats  = (float*)(ws + 200000);             // 3*256*4 = 3,072 B
    unsigned short* colidx = (unsigned short*)(ws + 203072);    // 50000*48*2 = 4,800,000 B
    unsigned short* wtb    = (unsigned short*)(ws + 5003072);   // 245,760 B
    unsigned short* gbuf   = (unsigned short*)(ws + 5248832);   // 131,072 B
    unsigned short* xa     = (unsigned short*)(ws + 5379904);   // (N+1) rows = 12,800,256 B
    unsigned short* xb     = (unsigned short*)(ws + 18180160);  // 12,800,256 B
    (void)in_sizes; (void)n_in; (void)out_size; (void)ws_size;

    hipMemsetAsync(ws, 0, 203072, stream);                      // cnt + stats (atomic targets)

    k_prep<<<SCAT_BLK + CVT_BLK + CVTW_BLK, 256, 0, stream>>>(
        edges, edges + N_EDGES, cnt, colidx, x, xa,
        conv_W1, conv_W2, head_W1, head_W2, wtb, xb);
    k_pad<<<(N_NODES + 255) / 256, 256, 0, stream>>>(cnt, colidx);

    // x lives in xa for every layer; h in xb. Stats accumulate via k_gml atomics.
    for (int l = 0; l < NLAYER; ++l) {
        k_gml<<<GBLK, 512, 0, stream>>>(xa, cnt, colidx,
                                        wtb + (2 * l) * HDIM * HDIM,
                                        conv_b1 + l * HDIM, xb, stats + l * 256);
        k_mlp2<<<NBLK, 256, 0, stream>>>(xb, stats + l * 256,
                                         conv_g + l * HDIM, conv_be + l * HDIM,
                                         wtb + (2 * l + 1) * HDIM * HDIM,
                                         conv_b2 + l * HDIM, xa);
    }

    k_pool<<<NGRAPH, 256, 0, stream>>>(xa, batch, gbuf);
    k_head<<<NGRAPH / 64, 256, 0, stream>>>(gbuf, wtb + 6 * HDIM * HDIM, head_b1,
                                            wtb + 7 * HDIM * HDIM, head_b2,
                                            (float*)d_out);
}